// Round 9
// baseline (153.486 us; speedup 1.0000x reference)
//
#include <hip/hip_runtime.h>

// MesoLayer R8: wave-private pipeline, ZERO block barriers.
// Each wave owns 32 rows = 8 chunks x 4 rows (4*390 fl = 390 float4, exact).
// Private LDS double-buffer per wave, staged via global_load_lds (7 VMEM
// instrs/chunk: 6 full-wave + 6-lane tail), ordered only by the wave's own
// counted s_waitcnt vmcnt(N). 12 independent waves/CU self-pace -> smooth
// aggregate issue (the 6.3 TB/s ubench regime), no lockstep bursts.
// Compute: 64 lanes = (r = ln>>4 in 0..3 rows) x (q = ln&15 j-groups);
// shfl_xor 1/2/4/8 reduces within each 16-lane q-group. Outputs collected in
// a per-wave LDS outbuf, flushed once per chunk as a 35-lane float4 store.

#define GLL16(gp, lp)                                                   \
  __builtin_amdgcn_global_load_lds(                                     \
      (const __attribute__((address_space(1))) void*)(gp),              \
      (__attribute__((address_space(3))) void*)(lp), 16, 0, 0)

static __device__ __forceinline__ float xsum16(float a) {
  a += __shfl_xor(a, 1, 64);
  a += __shfl_xor(a, 2, 64);
  a += __shfl_xor(a, 4, 64);
  a += __shfl_xor(a, 8, 64);
  return a;
}
static __device__ __forceinline__ float xmax16(float a) {
  a = fmaxf(a, __shfl_xor(a, 1, 64));
  a = fmaxf(a, __shfl_xor(a, 2, 64));
  a = fmaxf(a, __shfl_xor(a, 4, 64));
  a = fmaxf(a, __shfl_xor(a, 8, 64));
  return a;
}

// One segment over this wave's 4 rows. bp = wave buf + r*390 (row base),
// ob = outbuf + r*35. Lane-group q covers j in {q, q+16}. Mt = upper-tri of
// M = W W^T (scores[j] = sub[j]^T M subsum).
template<int L, int SEGOFF, int OUTOFF>
__device__ __forceinline__ void seg16(const float* __restrict__ bp, int q,
                                      const float (&Mt)[15],
                                      float* __restrict__ ob) {
  constexpr int T[5][5] = {{0, 1, 2, 3, 4},  {1, 5, 6, 7, 8},
                           {2, 6, 9, 10, 11}, {3, 7, 10, 12, 13},
                           {4, 8, 11, 13, 14}};
  constexpr int NJ = (L + 15) / 16;
  const bool lastv = (q + 16 * (NJ - 1)) < L;

  float s[NJ][5];
#pragma unroll
  for (int k = 0; k < NJ; ++k) {
    int j = q + 16 * k;
    if (j > L - 1) j = L - 1;  // only the last k can clamp
#pragma unroll
    for (int g = 0; g < 5; ++g) s[k][g] = bp[SEGOFF + j * 5 + g];
  }
#pragma unroll
  for (int g = 0; g < 5; ++g) s[NJ - 1][g] = lastv ? s[NJ - 1][g] : 0.f;

  float ssl[5];
#pragma unroll
  for (int g = 0; g < 5; ++g) {
    float a = s[0][g];
#pragma unroll
    for (int k = 1; k < NJ; ++k) a += s[k][g];
    ssl[g] = xsum16(a);  // full subsum on all lanes of the q-group
  }

  float v[5];
#pragma unroll
  for (int g = 0; g < 5; ++g) {
    float a = Mt[T[g][0]] * ssl[0];
#pragma unroll
    for (int h = 1; h < 5; ++h) a += Mt[T[g][h]] * ssl[h];
    v[g] = a;
  }

  float sc[NJ];
#pragma unroll
  for (int k = 0; k < NJ; ++k) {
    float a = s[k][0] * v[0];
#pragma unroll
    for (int g = 1; g < 5; ++g) a += s[k][g] * v[g];
    sc[k] = a;
  }
  sc[NJ - 1] = lastv ? sc[NJ - 1] : -3.0e38f;

  float ml = sc[0];
#pragma unroll
  for (int k = 1; k < NJ; ++k) ml = fmaxf(ml, sc[k]);
  float m = xmax16(ml);  // true max -> single-pass exp

  float d = 0.f, pl[5] = {0.f, 0.f, 0.f, 0.f, 0.f};
#pragma unroll
  for (int k = 0; k < NJ; ++k) {
    float e = __expf(sc[k] - m);  // masked k: exp(-huge)=0
    d += e;
#pragma unroll
    for (int g = 0; g < 5; ++g) pl[g] += e * s[k][g];
  }
  d = xsum16(d);
  float inv = 1.0f / d;
#pragma unroll
  for (int g = 0; g < 5; ++g) pl[g] = xsum16(pl[g]);
  if (q == 0) {
#pragma unroll
    for (int g = 0; g < 5; ++g) ob[OUTOFF + g] = pl[g] * inv;
  }
}

// LDS per wave (floats): buf0 [0,1560) | buf1 [1560,3120) | outbuf
// [3120,3260) | pad -> 3264 fl = 13056 B. 4 waves -> 52224 B -> 3 blocks/CU.
__global__ __launch_bounds__(256, 3) void meso_kernel(
    const float* __restrict__ x, const float* __restrict__ w,
    float* __restrict__ out) {
  __shared__ __align__(16) float smf[4 * 3264];
  float4* sm4 = (float4*)smf;
  const int t = threadIdx.x;
  const int wv = t >> 6, ln = t & 63, q = ln & 15, r = ln >> 4;
  const int W = blockIdx.x * 4 + wv;  // global wave id; rows [W*32, W*32+32)

  const float4* xw4 = (const float4*)x + (size_t)W * 3120;  // 32*390/4
  float4* o4 = (float4*)out + (size_t)W * 280;              // 32*35/4
  const int wb4 = wv * 816;   // wave LDS base, float4 units
  const int wbf = wv * 3264;  // wave LDS base, float units

  // Stage chunk c (390 fl4) into private buf b: 6 full-wave + 6-lane tail.
  auto stage = [&](int c, int b) {
    const float4* g = xw4 + c * 390;
    float4* l = sm4 + wb4 + b * 390;
#pragma unroll
    for (int i = 0; i < 6; ++i) GLL16(g + i * 64 + ln, l + i * 64 + ln);
    if (ln < 6) GLL16(g + 384 + ln, l + 384 + ln);
  };

  stage(0, 0);  // chunk 0 in flight...

  // ...while Mt = upper-tri(W W^T) resolves (uniform scalar loads, lgkm).
  float Mt[15];
  {
    int i = 0;
#pragma unroll
    for (int g = 0; g < 5; ++g)
#pragma unroll
      for (int h = g; h < 5; ++h, ++i) {
        float a = 0.f;
#pragma unroll
        for (int k = 0; k < 10; ++k) a += w[g * 10 + k] * w[h * 10 + k];
        Mt[i] = a;
      }
  }

#pragma unroll 1
  for (int i = 0; i < 8; ++i) {
    if (i < 7) stage(i + 1, (i + 1) & 1);
    // Counted wait for chunk i (per-wave audit): i=0: newer = stage(1)'s 7
    // loads. 1<=i<=6: newer = flush(i-1) store + stage(i+1)'s 7 = 8.
    // i=7: newer = flush(6) store only.
    if (i == 0)      asm volatile("s_waitcnt vmcnt(7)" ::: "memory");
    else if (i == 7) asm volatile("s_waitcnt vmcnt(1)" ::: "memory");
    else             asm volatile("s_waitcnt vmcnt(8)" ::: "memory");

    {
      const float* bp = smf + wbf + (i & 1) * 1560 + r * 390;
      float* ob = smf + wbf + 3120 + r * 35;
      seg16<5,  0,   0 >(bp, q, Mt, ob);
      seg16<9,  25,  5 >(bp, q, Mt, ob);
      seg16<9,  70,  10>(bp, q, Mt, ob);
      seg16<25, 115, 15>(bp, q, Mt, ob);
      seg16<9,  240, 20>(bp, q, Mt, ob);
      seg16<9,  285, 25>(bp, q, Mt, ob);
      seg16<12, 330, 30>(bp, q, Mt, ob);
    }

    // Flush this chunk's 4 rows (140 fl = 35 fl4, contiguous in global).
    asm volatile("s_waitcnt lgkmcnt(0)" ::: "memory");  // outbuf writes done
    if (ln < 35) o4[i * 35 + ln] = sm4[wb4 + 780 + ln];
  }
}

extern "C" void kernel_launch(void* const* d_in, const int* in_sizes, int n_in,
                              void* d_out, int out_size, void* d_ws, size_t ws_size,
                              hipStream_t stream) {
  const float* x = (const float*)d_in[0];
  const float* w = (const float*)d_in[1];
  float* out = (float*)d_out;
  int B = in_sizes[0] / 390;  // 131072
  int grid = B / 128;         // 1024 blocks (4 waves x 32 rows each)
  meso_kernel<<<grid, 256, 0, stream>>>(x, w, out);
}

// Round 10
// 47.252 us; speedup vs baseline: 3.2483x; 3.2483x over previous
//
#include <hip/hip_runtime.h>

// MesoLayer R9: R5's proven skeleton (best: 51.3us) with REGISTER staging
// (plain float4 loads -> ds_write) replacing global_load_lds DMA.
// Block = 256 threads = 256 rows, 16 chunks x 16 rows (1560 float4, flat
// contiguous). 2 LDS buffers + reg set A/B = 3-stage pipeline. Phase p:
//   flush(p-1) -> issue loads chunk(p+2)->regs -> compute(p) from buf[p&1]
//   -> counted vmcnt wait for chunk p+1 -> ds_write regs->buf[(p+1)&1]
//   -> lgkm0 + s_barrier.
// Loads are in flight one full phase (~3us >> HBM latency); the plain-load
// path is the 6.3 TB/s-proven one (m13), vs gll-DMA's apparent ~16GB/s/CU cap.

static __device__ __forceinline__ float xsum(float a) {
  a += __shfl_xor(a, 16, 64);
  a += __shfl_xor(a, 32, 64);
  return a;
}
static __device__ __forceinline__ float xmax(float a) {
  a = fmaxf(a, __shfl_xor(a, 16, 64));
  a = fmaxf(a, __shfl_xor(a, 32, 64));
  return a;
}

// 64-lane segment (R5-proven): lane (q=ln>>4, r=ln&15) covers row r,
// j in {q, q+4, ...}; reduce over q via shfl_xor 16/32; true global max ->
// single-pass exp. Mt = upper-tri of M = W W^T.
template<int L, int SEGOFF, int OUTOFF>
__device__ __forceinline__ void seg64(const float* __restrict__ bp, int q,
                                      const float (&Mt)[15],
                                      float* __restrict__ ob) {
  constexpr int T[5][5] = {{0, 1, 2, 3, 4},  {1, 5, 6, 7, 8},
                           {2, 6, 9, 10, 11}, {3, 7, 10, 12, 13},
                           {4, 8, 11, 13, 14}};
  constexpr int NJ = (L + 3) / 4;
  const bool lastv = (q + 4 * (NJ - 1)) < L;

  float s[NJ][5];
#pragma unroll
  for (int k = 0; k < NJ; ++k) {
    int j = q + 4 * k;
    if (j > L - 1) j = L - 1;  // only last k can clamp
#pragma unroll
    for (int g = 0; g < 5; ++g) s[k][g] = bp[SEGOFF + j * 5 + g];
  }
#pragma unroll
  for (int g = 0; g < 5; ++g) s[NJ - 1][g] = lastv ? s[NJ - 1][g] : 0.f;

  float ssl[5];
#pragma unroll
  for (int g = 0; g < 5; ++g) {
    float a = s[0][g];
#pragma unroll
    for (int k = 1; k < NJ; ++k) a += s[k][g];
    ssl[g] = xsum(a);  // full subsum on all lanes
  }

  float v[5];
#pragma unroll
  for (int g = 0; g < 5; ++g) {
    float a = Mt[T[g][0]] * ssl[0];
#pragma unroll
    for (int h = 1; h < 5; ++h) a += Mt[T[g][h]] * ssl[h];
    v[g] = a;
  }

  float sc[NJ];
#pragma unroll
  for (int k = 0; k < NJ; ++k) {
    float a = s[k][0] * v[0];
#pragma unroll
    for (int g = 1; g < 5; ++g) a += s[k][g] * v[g];
    sc[k] = a;
  }
  sc[NJ - 1] = lastv ? sc[NJ - 1] : -3.0e38f;

  float ml = sc[0];
#pragma unroll
  for (int k = 1; k < NJ; ++k) ml = fmaxf(ml, sc[k]);
  float m = xmax(ml);

  float d = 0.f, pl[5] = {0.f, 0.f, 0.f, 0.f, 0.f};
#pragma unroll
  for (int k = 0; k < NJ; ++k) {
    float e = __expf(sc[k] - m);  // masked k: exp(-huge)=0
    d += e;
#pragma unroll
    for (int g = 0; g < 5; ++g) pl[g] += e * s[k][g];
  }
  d = xsum(d);
  float inv = 1.0f / d;
#pragma unroll
  for (int g = 0; g < 5; ++g) pl[g] = xsum(pl[g]);
  if (q == 0) {
#pragma unroll
    for (int g = 0; g < 5; ++g) ob[OUTOFF + g] = pl[g] * inv;
  }
}

// LDS (float4 units): buf0 [0,1560) | buf1 [1560,3120) | outbuf [3120,3400)
// = 54.4 KB -> 2 blocks/CU.
__global__ __launch_bounds__(256, 2) void meso_kernel(
    const float* __restrict__ x, const float* __restrict__ w,
    float* __restrict__ out) {
  __shared__ __align__(16) float4 sm4[3400];
  float* smf = (float*)sm4;
  const int t = threadIdx.x;
  const int wv = t >> 6, ln = t & 63, q = ln >> 4, r = ln & 15;
  const size_t blk = blockIdx.x;
  const float4* xp4 = (const float4*)x + blk * 24960;  // 256*390/4
  float4* o4 = (float4*)out + blk * 2240;              // 256*35/4

  float4 A0, A1, A2, A3, A4, A5, A6 = make_float4(0, 0, 0, 0);
  float4 B0, B1, B2, B3, B4, B5, B6 = make_float4(0, 0, 0, 0);

  // Stage-issue chunk c into reg set (6 full loads + wave3 tail of 24).
#define ISSUE(R, c)                                                    \
  { const float4* g_ = xp4 + (size_t)(c) * 1560;                       \
    R##0 = g_[t];        R##1 = g_[t + 256];  R##2 = g_[t + 512];      \
    R##3 = g_[t + 768];  R##4 = g_[t + 1024]; R##5 = g_[t + 1280];     \
    if (t >= 232) R##6 = g_[1304 + t]; }

#define WRITE(R, b)                                                    \
  { float4* l_ = sm4 + (b) * 1560;                                     \
    l_[t] = R##0;        l_[t + 256] = R##1;  l_[t + 512] = R##2;      \
    l_[t + 768] = R##3;  l_[t + 1024] = R##4; l_[t + 1280] = R##5;     \
    if (t >= 232) l_[1304 + t] = R##6; }

  // Counted wait for the chunk about to be WRITTEN: n = #VMEM ops issued
  // after that chunk's last load (wave3 issues 7 loads/chunk, others 6).
#define WAITC(n03, n3)                                                 \
  { if (wv == 3) asm volatile("s_waitcnt vmcnt(" #n3 ")" ::: "memory");\
    else         asm volatile("s_waitcnt vmcnt(" #n03 ")" ::: "memory"); }

#define BAR()                                                          \
  { asm volatile("s_waitcnt lgkmcnt(0)" ::: "memory");                 \
    __builtin_amdgcn_s_barrier();                                      \
    __builtin_amdgcn_sched_barrier(0); }

#define FLUSH(pp)                                                      \
  { if (ln < 35)                                                       \
      o4[(size_t)(pp) * 140 + wv * 35 + ln] =                          \
          sm4[3120 + ((pp) & 1) * 140 + wv * 35 + ln]; }

#define COMPUTE(par)                                                   \
  { const float* bp = smf + (par) * 6240 + r * 390;                    \
    float* ob = smf + 12480 + (par) * 560 + r * 35;                    \
    if (wv == 0) { seg64<25, 115, 15>(bp, q, Mt, ob); }                \
    else if (wv == 1) { seg64<12, 330, 30>(bp, q, Mt, ob);             \
                        seg64<5,  0,   0 >(bp, q, Mt, ob); }           \
    else if (wv == 2) { seg64<9,  25,  5 >(bp, q, Mt, ob);             \
                        seg64<9,  70,  10>(bp, q, Mt, ob); }           \
    else              { seg64<9,  240, 20>(bp, q, Mt, ob);             \
                        seg64<9,  285, 25>(bp, q, Mt, ob); } }

  ISSUE(A, 0)
  ISSUE(B, 1)

  // Mt = upper-tri(W W^T) from uniform scalar loads, overlapping load latency.
  float Mt[15];
  {
    int i = 0;
#pragma unroll
    for (int g = 0; g < 5; ++g)
#pragma unroll
      for (int h = g; h < 5; ++h, ++i) {
        float a = 0.f;
#pragma unroll
        for (int k = 0; k < 10; ++k) a += w[g * 10 + k] * w[h * 10 + k];
        Mt[i] = a;
      }
  }

  WAITC(6, 7)      // chunk0 complete (newer = chunk1's 6/7 loads)
  WRITE(A, 0)
  BAR()

#pragma unroll 1
  for (int p = 0; p < 16; p += 2) {
    // ---- even phase p: compute buf0/out0; B holds chunk p+1 ----
    if (p > 0) FLUSH(p - 1)
    if (p + 2 < 16) ISSUE(A, p + 2)
    COMPUTE(0)
    if (p == 0)       WAITC(6, 7)   // newer = issue(p+2) only
    else if (p < 14)  WAITC(7, 8)   // newer = flush store + issue(p+2)
    else              WAITC(1, 1)   // p=14: newer = flush store only
    WRITE(B, 1)
    BAR()

    // ---- odd phase p+1: compute buf1/out1; A holds chunk p+2 ----
    FLUSH(p)
    if (p + 3 < 16) ISSUE(B, p + 3)
    COMPUTE(1)
    if (p + 2 < 16) {
      if (p + 1 < 14) WAITC(7, 8)
      else            WAITC(1, 1)   // p+1=13? no: p+1<=13 covered above; p+1=15 has no write
      WRITE(A, 0)
    }
    BAR()
  }
  FLUSH(15)
}

extern "C" void kernel_launch(void* const* d_in, const int* in_sizes, int n_in,
                              void* d_out, int out_size, void* d_ws, size_t ws_size,
                              hipStream_t stream) {
  const float* x = (const float*)d_in[0];
  const float* w = (const float*)d_in[1];
  float* out = (float*)d_out;
  int B = in_sizes[0] / 390;  // 131072
  int grid = B / 256;         // 512 blocks = 2/CU, all resident
  meso_kernel<<<grid, 256, 0, stream>>>(x, w, out);
}